// Round 1
// baseline (704.594 us; speedup 1.0000x reference)
//
#include <hip/hip_runtime.h>

// AvgPool2d, kernel=3, stride=2, VALID.
// x: (8, 64, 512, 512) fp32  ->  out: (8, 64, 255, 255) fp32
//
// Each thread computes TWO horizontally-adjacent output pixels (ow0=2t, ow0+1).
// Their 3x3 windows cover input columns [4t, 4t+4]: one float4 load + one
// scalar per input row -> fully coalesced 16B loads despite stride 2.

#define IN_N 8
#define IN_C 64
#define IN_H 512
#define IN_W 512
#define OUT_H 255
#define OUT_W 255

__global__ __launch_bounds__(128) void KeyedAvgpool2d_kernel(
    const float* __restrict__ in, float* __restrict__ out) {
    const int t   = threadIdx.x;   // 0..127, each covers 2 output cols
    const int oh  = blockIdx.y;    // 0..254
    const int nc  = blockIdx.z;    // 0..511 (N*C)
    const int ow0 = 2 * t;
    if (ow0 >= OUT_W) return;

    const float* base = in + (size_t)nc * (IN_H * IN_W)
                           + (size_t)(2 * oh) * IN_W
                           + 4 * t;   // 16B aligned: row base is 2KB aligned
    float s0 = 0.0f, s1 = 0.0f;
#pragma unroll
    for (int r = 0; r < 3; ++r) {
        const float* row = base + r * IN_W;
        float4 v = *(const float4*)row;  // cols 4t .. 4t+3
        float  e = row[4];               // col  4t+4 (always in-bounds)
        s0 += v.x + v.y + v.z;           // window for ow0
        s1 += v.z + v.w + e;             // window for ow0+1
    }

    float* orow = out + (size_t)nc * (OUT_H * OUT_W) + (size_t)oh * OUT_W + ow0;
    const float inv9 = 1.0f / 9.0f;
    orow[0] = s0 * inv9;
    if (ow0 + 1 < OUT_W) orow[1] = s1 * inv9;   // t=127 writes only ow=254
}

extern "C" void kernel_launch(void* const* d_in, const int* in_sizes, int n_in,
                              void* d_out, int out_size, void* d_ws, size_t ws_size,
                              hipStream_t stream) {
    const float* x = (const float*)d_in[0];
    float* out = (float*)d_out;

    dim3 block(128, 1, 1);
    dim3 grid(1, OUT_H, IN_N * IN_C);   // (x-pairs, output row, n*c plane)
    KeyedAvgpool2d_kernel<<<grid, block, 0, stream>>>(x, out);
}

// Round 2
// 703.806 us; speedup vs baseline: 1.0011x; 1.0011x over previous
//
#include <hip/hip_runtime.h>

// AvgPool2d k=3 s=2 VALID. x: (8,64,512,512) fp32 -> out: (8,64,255,255) fp32.
//
// Each thread computes a 2(row) x 4(col) patch of outputs:
//   out rows oh0, oh0+1 ; out cols 4t..4t+3  (t = lane 0..63)
// Input needed: rows 4p..4p+4 (5 rows, middle row shared between the two
// output rows -> 2.5 input rows per output row vs 3 for the naive shape),
// cols 8t..8t+8 (two aligned float4 loads + 1 scalar; one 64-lane wave
// spans the full 512-col row -> perfectly coalesced 2KB row reads).

#define IN_H 512
#define IN_W 512
#define OUT_H 255
#define OUT_W 255
#define PLANES 512  // N*C = 8*64

__global__ __launch_bounds__(256) void KeyedAvgpool2d_kernel(
    const float* __restrict__ in, float* __restrict__ out) {
    const int tid = threadIdx.x;
    const int t   = tid & 63;               // lane -> out cols 4t..4t+3
    const int g   = tid >> 6;               // wave -> oh-pair within block
    const int p   = blockIdx.x * 4 + g;     // oh-pair index 0..127
    const int nc  = blockIdx.y;             // plane 0..511
    const int oh0 = 2 * p;                  // 0,2,..,254
    const bool has2 = (oh0 + 1) < OUT_H;    // p==127 -> only oh0=254

    const float* plane = in + (size_t)nc * (IN_H * IN_W);

    float a00 = 0, a01 = 0, a02 = 0, a03 = 0;   // rows r..r+2  (oh0)
    float a10 = 0, a11 = 0, a12 = 0, a13 = 0;   // rows r+2..r+4 (oh0+1)
#pragma unroll
    for (int r = 0; r < 5; ++r) {
        int ir = 2 * oh0 + r;
        ir = ir > (IN_H - 1) ? (IN_H - 1) : ir;     // p==127,r==4 clamp (unused result)
        const float* row = plane + (size_t)ir * IN_W + 8 * t;
        float4 v0 = *(const float4*)row;            // cols 8t..8t+3 (16B aligned)
        float4 v1 = *(const float4*)(row + 4);      // cols 8t+4..8t+7
        float  c8 = (t < 63) ? row[8] : 0.0f;       // col 8t+8 (edge lane skips)
        float h0 = v0.x + v0.y + v0.z;
        float h1 = v0.z + v0.w + v1.x;
        float h2 = v1.x + v1.y + v1.z;
        float h3 = v1.z + v1.w + c8;
        if (r < 3)  { a00 += h0; a01 += h1; a02 += h2; a03 += h3; }
        if (r >= 2) { a10 += h0; a11 += h1; a12 += h2; a13 += h3; }
    }

    const float inv9 = 1.0f / 9.0f;
    float* o0 = out + (size_t)nc * (OUT_H * OUT_W) + (size_t)oh0 * OUT_W + 4 * t;
    o0[0] = a00 * inv9;
    o0[1] = a01 * inv9;
    o0[2] = a02 * inv9;
    if (t < 63) o0[3] = a03 * inv9;     // lane 63: out col 255 doesn't exist
    if (has2) {
        float* o1 = o0 + OUT_W;
        o1[0] = a10 * inv9;
        o1[1] = a11 * inv9;
        o1[2] = a12 * inv9;
        if (t < 63) o1[3] = a13 * inv9;
    }
}

extern "C" void kernel_launch(void* const* d_in, const int* in_sizes, int n_in,
                              void* d_out, int out_size, void* d_ws, size_t ws_size,
                              hipStream_t stream) {
    const float* x = (const float*)d_in[0];
    float* out = (float*)d_out;

    dim3 block(256, 1, 1);                 // 4 waves = 4 oh-pairs
    dim3 grid(32, PLANES, 1);              // 32*4 = 128 oh-pairs ; 512 planes
    KeyedAvgpool2d_kernel<<<grid, block, 0, stream>>>(x, out);
}